// Round 4
// baseline (213.017 us; speedup 1.0000x reference)
//
#include <hip/hip_runtime.h>
#include <hip/hip_bf16.h>

// Embedding gather: out[t, :] = table[ids[t], :]
// B=8, S=2048 -> 16384 tokens; E=768 fp32 = 192 float4 per row.
// One 64-lane wave per token; each lane moves 3 float4 (48 B).
//
// Stores are nontemporal: out is write-once and never re-read, so stream it
// past L2/L3 and keep cache capacity for the 154 MB table (gather reuse).
// Note: __builtin_nontemporal_store requires a native clang vector type,
// not HIP_vector_type<float,4> -- use ext_vector_type(4).

typedef float f32x4 __attribute__((ext_vector_type(4)));

#define EMB_F4 192          // 768 floats / 4

__global__ __launch_bounds__(256) void embed_gather_kernel(
    const int* __restrict__ ids,
    const f32x4* __restrict__ table,
    f32x4* __restrict__ out,
    int n_tokens)
{
    const int gtid  = blockIdx.x * blockDim.x + threadIdx.x;
    const int token = gtid >> 6;          // one wave (64 lanes) per token
    const int lane  = threadIdx.x & 63;
    if (token >= n_tokens) return;

    const int row = ids[token];           // wave-uniform load (broadcast)

    const f32x4* __restrict__ src = table + (size_t)row   * EMB_F4;
    f32x4*       __restrict__ dst = out   + (size_t)token * EMB_F4;

    // Load all three float4 first (3 independent 16B loads in flight),
    // then stream the stores nontemporally.
    f32x4 r0 = src[lane];
    f32x4 r1 = src[lane + 64];
    f32x4 r2 = src[lane + 128];

    __builtin_nontemporal_store(r0, &dst[lane]);
    __builtin_nontemporal_store(r1, &dst[lane + 64]);
    __builtin_nontemporal_store(r2, &dst[lane + 128]);
}

extern "C" void kernel_launch(void* const* d_in, const int* in_sizes, int n_in,
                              void* d_out, int out_size, void* d_ws, size_t ws_size,
                              hipStream_t stream)
{
    const int*   ids   = (const int*)d_in[0];      // [B*S] token ids (int32 per harness)
    const float* table = (const float*)d_in[1];    // [VOCAB, 768] fp32
    float*       out   = (float*)d_out;            // [B*S, 768] fp32

    const int n_tokens = in_sizes[0];              // 16384

    // 4 tokens per 256-thread block (one wave each)
    const int blocks = (n_tokens + 3) / 4;
    embed_gather_kernel<<<blocks, 256, 0, stream>>>(
        ids, (const f32x4*)table, (f32x4*)out, n_tokens);
}